// Round 10
// baseline (143.793 us; speedup 1.0000x reference)
//
#include <hip/hip_runtime.h>
#include <hip/hip_bf16.h>

#define J_DIM 25
#define T_DIM 120
#define O_DIM 64
#define KPAD  328        // bf16 per ys row; 656 B = 164 dwords == 4 mod 32 -> 2-way banks
#define TB    16         // t-rows per block (all rows valid; last chunk overlaps)
#define WROWS 20         // staged window rows (tloc + w <= 19)
#define XPAD  20         // xs row pad (floats)

typedef __attribute__((ext_vector_type(8))) short bf16x8;
typedef __attribute__((ext_vector_type(4))) float f32x4;

__device__ __forceinline__ unsigned f2bf(float f) {
    union { float f; unsigned u; } v; v.f = f;
    return (v.u + 0x7FFFu + ((v.u >> 16) & 1u)) >> 16;
}
__device__ __forceinline__ unsigned pk2(float lo, float hi) {
    __hip_bfloat162 h = __float22bfloat162_rn(float2{lo, hi});
    unsigned u;
    __builtin_memcpy(&u, &h, 4);
    return u;
}

// ---- W (306x64 f32) -> Wf[o][k], k = 18a + b; b<17: 0.5*W2[a,b]; b==17: W1[a] ----
__global__ void wprep(const float* __restrict__ W, unsigned short* __restrict__ Wf) {
    int i = blockIdx.x * 256 + threadIdx.x;
    if (i >= O_DIM * KPAD) return;
    int o = i / KPAD, k = i % KPAD;
    int a = k / 18, b = k % 18;
    float v = 0.0f;
    if (k < 306) v = (b == 17) ? W[a * O_DIM + o] : 0.5f * W[(17 + 17 * a + b) * O_DIM + o];
    Wf[o * KPAD + k] = (unsigned short)f2bf(v);
}

// ---- main: block = (n, j, 16-t chunk); 128 threads; flat 2-barrier structure ----
__global__ __launch_bounds__(128, 6) void sig_mfma(
    const float* __restrict__ x, const unsigned short* __restrict__ Wf,
    const float* __restrict__ bias, float* __restrict__ out)
{
    __shared__ float xs[WROWS][XPAD];            // 1,600 B
    __shared__ unsigned short ys[TB * KPAD];     // 10,496 B   (total 12.1 KB -> ~13 blk/CU)

    const int tid = threadIdx.x;
    const int bid = blockIdx.x;
    const int chunk = bid & 7;
    const int j  = (bid >> 3) % J_DIM;
    const int n  = bid / (8 * J_DIM);
    const int t0 = (chunk < 7) ? chunk * 16 : 104;   // last chunk overlaps (identical rows)
    const int wave = tid >> 6, lane = tid & 63;
    const int l15 = lane & 15, l4 = lane >> 4;

    // ---- stage xs[i][c] = x[n,c,j,clamp(t0-2+i)] ----
    const float* xbase = x + ((size_t)(n * 16) * J_DIM + j) * T_DIM;
    for (int idx = tid; idx < 16 * WROWS; idx += 128) {
        int i = idx % WROWS, c = idx / WROWS;
        int st = min(max(t0 - 2 + i, 0), T_DIM - 1);
        xs[i][c] = xbase[(size_t)c * J_DIM * T_DIM + st];
    }
    // zero pad bytes [608,656) of every row (k = 304..327; 608-611 re-written in phase 1)
    if (tid < TB * 3) {
        int r = tid / 3, p = tid % 3;
        *(uint4*)((char*)ys + r * 656 + 608 + p * 16) = uint4{0, 0, 0, 0};
    }
    __syncthreads();

    // ---- phase 1: thread (tloc, q) -> S2 rows a = 2q, 2q+1 (+ row 16 by q==0) ----
    // S2[a,b] = sum_w h_w[a] * p_w[b],  h = (-p1, p0-p2, p1-p3, p2-p4, p3+p4)
    {
        const int tl8 = lane & 7, q = lane >> 3;
        const int tloc = wave * 8 + tl8;             // 0..15, all active
        const int t = t0 + tloc;
        const int start = max(t - 2, 0), end = min(t + 3, T_DIM);
        const float inv = 1.0f / (float)(end - start - 1);
        float ptv[5];
        #pragma unroll
        for (int w = 0; w < 5; ++w) {
            int pcw = min(max(t - 2 + w, 0), T_DIM - 1);
            ptv[w] = (float)(pcw - start) * inv;
        }
        float pa0[5], pa1[5];
        #pragma unroll
        for (int w = 0; w < 5; ++w) {
            float2 pr = *(const float2*)&xs[tloc + w][2 * q];
            pa0[w] = pr.x; pa1[w] = pr.y;
        }
        float h0[5], h1[5], ht[5];
        h0[0] = -pa0[1];          h1[0] = -pa1[1];          ht[0] = -ptv[1];
        h0[1] = pa0[0] - pa0[2];  h1[1] = pa1[0] - pa1[2];  ht[1] = ptv[0] - ptv[2];
        h0[2] = pa0[1] - pa0[3];  h1[2] = pa1[1] - pa1[3];  ht[2] = ptv[1] - ptv[3];
        h0[3] = pa0[2] - pa0[4];  h1[3] = pa1[2] - pa1[4];  ht[3] = ptv[2] - ptv[4];
        h0[4] = pa0[3] + pa0[4];  h1[4] = pa1[3] + pa1[4];  ht[4] = ptv[3] + ptv[4];

        unsigned u0[9], u1[9], ut[9];
        float accp0 = 0, accp1 = 0, accpt = 0;
        #pragma unroll
        for (int hb = 0; hb < 2; ++hb) {
            float4 xw[5][2];
            #pragma unroll
            for (int w = 0; w < 5; ++w) {
                const float* rw = &xs[tloc + w][0];
                xw[w][0] = *(const float4*)(rw + 8 * hb);
                xw[w][1] = *(const float4*)(rw + 8 * hb + 4);
            }
            #pragma unroll
            for (int b8 = 0; b8 < 8; ++b8) {
                float pb[5];
                #pragma unroll
                for (int w = 0; w < 5; ++w) {
                    float4 v = xw[w][b8 >> 2];
                    pb[w] = ((b8 & 3) == 0) ? v.x : ((b8 & 3) == 1) ? v.y
                          : ((b8 & 3) == 2) ? v.z : v.w;
                }
                float a0 = h0[0] * pb[0], a1 = h1[0] * pb[0], at = ht[0] * pb[0];
                #pragma unroll
                for (int w = 1; w < 5; ++w) {
                    a0 = fmaf(h0[w], pb[w], a0);
                    a1 = fmaf(h1[w], pb[w], a1);
                    at = fmaf(ht[w], pb[w], at);
                }
                const int b = hb * 8 + b8;
                if (b & 1) {
                    const int m = b >> 1;
                    u0[m] = pk2(accp0, a0);
                    u1[m] = pk2(accp1, a1);
                    ut[m] = pk2(accpt, at);
                } else { accp0 = a0; accp1 = a1; accpt = at; }
            }
        }
        {   // b = 16 (time column) + S1 slot
            float a0 = h0[0] * ptv[0], a1 = h1[0] * ptv[0], at = ht[0] * ptv[0];
            #pragma unroll
            for (int w = 1; w < 5; ++w) {
                a0 = fmaf(h0[w], ptv[w], a0);
                a1 = fmaf(h1[w], ptv[w], a1);
                at = fmaf(ht[w], ptv[w], at);
            }
            u0[8] = pk2(a0, pa0[4]);
            u1[8] = pk2(a1, pa1[4]);
            ut[8] = pk2(at, ptv[4]);
        }
        char* yr = (char*)ys + tloc * 656 + 72 * q;  // rows 2q,2q+1: contiguous 72 B
        *(uint2*)(yr +  0) = uint2{u0[0], u0[1]};
        *(uint2*)(yr +  8) = uint2{u0[2], u0[3]};
        *(uint2*)(yr + 16) = uint2{u0[4], u0[5]};
        *(uint2*)(yr + 24) = uint2{u0[6], u0[7]};
        *(uint2*)(yr + 32) = uint2{u0[8], u1[0]};
        *(uint2*)(yr + 40) = uint2{u1[1], u1[2]};
        *(uint2*)(yr + 48) = uint2{u1[3], u1[4]};
        *(uint2*)(yr + 56) = uint2{u1[5], u1[6]};
        *(uint2*)(yr + 64) = uint2{u1[7], u1[8]};
        if (q == 0) {                                // row a=16 at bytes [576,612)
            char* yr16 = (char*)ys + tloc * 656 + 576;
            *(uint2*)(yr16 +  0) = uint2{ut[0], ut[1]};
            *(uint2*)(yr16 +  8) = uint2{ut[2], ut[3]};
            *(uint2*)(yr16 + 16) = uint2{ut[4], ut[5]};
            *(uint2*)(yr16 + 24) = uint2{ut[6], ut[7]};
            *(unsigned*)(yr16 + 32) = ut[8];
        }
    }
    __syncthreads();

    // ---- phase 2: 2 waves = o-halves; y (16x320) @ Wf^T; B-frags global (L2-hot) ----
    {
        f32x4 acc[2];
        #pragma unroll
        for (int cc = 0; cc < 2; ++cc) {
            float bv = bias[(wave * 2 + cc) * 16 + l15];
            acc[cc] = f32x4{bv, bv, bv, bv};
        }
        const char* Ab = (const char*)ys + l15 * 656 + l4 * 16;
        const unsigned short* Bb = Wf + (size_t)l15 * KPAD + l4 * 8;
        #pragma unroll
        for (int kk = 0; kk < 10; ++kk) {
            bf16x8 af = *(const bf16x8*)(Ab + kk * 64);
            #pragma unroll
            for (int cc = 0; cc < 2; ++cc) {
                bf16x8 bfr = *(const bf16x8*)(Bb + (size_t)((wave * 2 + cc) * 16) * KPAD + kk * 32);
                acc[cc] = __builtin_amdgcn_mfma_f32_16x16x32_bf16(af, bfr, acc[cc], 0, 0, 0);
            }
        }
        const int tg = t0 + l4 * 4;                  // row = l4*4 + reg -> t
        #pragma unroll
        for (int cc = 0; cc < 2; ++cc) {
            int o = (wave * 2 + cc) * 16 + l15;
            *(f32x4*)(out + ((size_t)(n * O_DIM + o) * J_DIM + j) * T_DIM + tg) = acc[cc];
        }
    }
}

extern "C" void kernel_launch(void* const* d_in, const int* in_sizes, int n_in,
                              void* d_out, int out_size, void* d_ws, size_t ws_size,
                              hipStream_t stream) {
    const float* x = (const float*)d_in[0];
    const float* W = (const float*)d_in[1];
    const float* b = (const float*)d_in[2];
    float* out = (float*)d_out;
    unsigned short* Wf = (unsigned short*)d_ws;   // 64*328*2 = 41,984 B

    wprep<<<(O_DIM * KPAD + 255) / 256, 256, 0, stream>>>(W, Wf);
    sig_mfma<<<64 * J_DIM * 8, 128, 0, stream>>>(x, Wf, b, out);
}

// Round 11
// 57.515 us; speedup vs baseline: 2.5001x; 2.5001x over previous
//
#include <hip/hip_runtime.h>
#include <hip/hip_bf16.h>

#define J_DIM 25
#define T_DIM 120
#define O_DIM 64
#define KPAD  328        // bf16 per ys row; 656 B = 164 dwords == 4 mod 32 -> 2-way banks
#define TB    16         // t-rows per block (all rows valid; last chunk overlaps)
#define WROWS 20         // staged window rows (tloc + w <= 19)
#define XPAD  20         // xs row pad (floats)

typedef __attribute__((ext_vector_type(8))) short bf16x8;
typedef __attribute__((ext_vector_type(4))) float f32x4;

__device__ __forceinline__ unsigned f2bf(float f) {
    union { float f; unsigned u; } v; v.f = f;
    return (v.u + 0x7FFFu + ((v.u >> 16) & 1u)) >> 16;
}
__device__ __forceinline__ unsigned pk2(float lo, float hi) {
    __hip_bfloat162 h = __float22bfloat162_rn(float2{lo, hi});
    unsigned u;
    __builtin_memcpy(&u, &h, 4);
    return u;
}

// ---- W (306x64 f32) -> Wf[o][k], k = 18a + b; b<17: 0.5*W2[a,b]; b==17: W1[a] ----
__global__ void wprep(const float* __restrict__ W, unsigned short* __restrict__ Wf) {
    int i = blockIdx.x * 256 + threadIdx.x;
    if (i >= O_DIM * KPAD) return;
    int o = i / KPAD, k = i % KPAD;
    int a = k / 18, b = k % 18;
    float v = 0.0f;
    if (k < 306) v = (b == 17) ? W[a * O_DIM + o] : 0.5f * W[(17 + 17 * a + b) * O_DIM + o];
    Wf[o * KPAD + k] = (unsigned short)f2bf(v);
}

// ---- main: block = (n, j, 16-t chunk); 128 threads; flat 2-barrier structure ----
// NOTE: launch_bounds 2nd arg must stay <= 4: at 6 the allocator clamps to 40 VGPR
// (needs ~56) and spills -> 200+ MB scratch traffic (measured R6, R10).
__global__ __launch_bounds__(128, 4) void sig_mfma(
    const float* __restrict__ x, const unsigned short* __restrict__ Wf,
    const float* __restrict__ bias, float* __restrict__ out)
{
    __shared__ float xs[WROWS][XPAD];            // 1,600 B
    __shared__ unsigned short ys[TB * KPAD];     // 10,496 B   (total 12.1 KB -> ~13 blk/CU)

    const int tid = threadIdx.x;
    const int bid = blockIdx.x;
    const int chunk = bid & 7;
    const int j  = (bid >> 3) % J_DIM;
    const int n  = bid / (8 * J_DIM);
    const int t0 = (chunk < 7) ? chunk * 16 : 104;   // last chunk overlaps (identical rows)
    const int wave = tid >> 6, lane = tid & 63;
    const int l15 = lane & 15, l4 = lane >> 4;

    // ---- stage xs[i][c] = x[n,c,j,clamp(t0-2+i)] ----
    const float* xbase = x + ((size_t)(n * 16) * J_DIM + j) * T_DIM;
    for (int idx = tid; idx < 16 * WROWS; idx += 128) {
        int i = idx % WROWS, c = idx / WROWS;
        int st = min(max(t0 - 2 + i, 0), T_DIM - 1);
        xs[i][c] = xbase[(size_t)c * J_DIM * T_DIM + st];
    }
    // zero pad bytes [608,656) of every row (k = 304..327; 608-611 re-written in phase 1)
    if (tid < TB * 3) {
        int r = tid / 3, p = tid % 3;
        *(uint4*)((char*)ys + r * 656 + 608 + p * 16) = uint4{0, 0, 0, 0};
    }
    __syncthreads();

    // ---- phase 1: thread (tloc, q) -> S2 rows a = 2q, 2q+1 (+ row 16 by q==0) ----
    // S2[a,b] = sum_w h_w[a] * p_w[b],  h = (-p1, p0-p2, p1-p3, p2-p4, p3+p4)
    {
        const int tl8 = lane & 7, q = lane >> 3;
        const int tloc = wave * 8 + tl8;             // 0..15, all active
        const int t = t0 + tloc;
        const int start = max(t - 2, 0), end = min(t + 3, T_DIM);
        const float inv = 1.0f / (float)(end - start - 1);
        float ptv[5];
        #pragma unroll
        for (int w = 0; w < 5; ++w) {
            int pcw = min(max(t - 2 + w, 0), T_DIM - 1);
            ptv[w] = (float)(pcw - start) * inv;
        }
        float pa0[5], pa1[5];
        #pragma unroll
        for (int w = 0; w < 5; ++w) {
            float2 pr = *(const float2*)&xs[tloc + w][2 * q];
            pa0[w] = pr.x; pa1[w] = pr.y;
        }
        float h0[5], h1[5], ht[5];
        h0[0] = -pa0[1];          h1[0] = -pa1[1];          ht[0] = -ptv[1];
        h0[1] = pa0[0] - pa0[2];  h1[1] = pa1[0] - pa1[2];  ht[1] = ptv[0] - ptv[2];
        h0[2] = pa0[1] - pa0[3];  h1[2] = pa1[1] - pa1[3];  ht[2] = ptv[1] - ptv[3];
        h0[3] = pa0[2] - pa0[4];  h1[3] = pa1[2] - pa1[4];  ht[3] = ptv[2] - ptv[4];
        h0[4] = pa0[3] + pa0[4];  h1[4] = pa1[3] + pa1[4];  ht[4] = ptv[3] + ptv[4];

        unsigned u0[9], u1[9], ut[9];
        float accp0 = 0, accp1 = 0, accpt = 0;
        #pragma unroll
        for (int hb = 0; hb < 2; ++hb) {
            float4 xw[5][2];
            #pragma unroll
            for (int w = 0; w < 5; ++w) {
                const float* rw = &xs[tloc + w][0];
                xw[w][0] = *(const float4*)(rw + 8 * hb);
                xw[w][1] = *(const float4*)(rw + 8 * hb + 4);
            }
            #pragma unroll
            for (int b8 = 0; b8 < 8; ++b8) {
                float pb[5];
                #pragma unroll
                for (int w = 0; w < 5; ++w) {
                    float4 v = xw[w][b8 >> 2];
                    pb[w] = ((b8 & 3) == 0) ? v.x : ((b8 & 3) == 1) ? v.y
                          : ((b8 & 3) == 2) ? v.z : v.w;
                }
                float a0 = h0[0] * pb[0], a1 = h1[0] * pb[0], at = ht[0] * pb[0];
                #pragma unroll
                for (int w = 1; w < 5; ++w) {
                    a0 = fmaf(h0[w], pb[w], a0);
                    a1 = fmaf(h1[w], pb[w], a1);
                    at = fmaf(ht[w], pb[w], at);
                }
                const int b = hb * 8 + b8;
                if (b & 1) {
                    const int m = b >> 1;
                    u0[m] = pk2(accp0, a0);
                    u1[m] = pk2(accp1, a1);
                    ut[m] = pk2(accpt, at);
                } else { accp0 = a0; accp1 = a1; accpt = at; }
            }
        }
        {   // b = 16 (time column) + S1 slot
            float a0 = h0[0] * ptv[0], a1 = h1[0] * ptv[0], at = ht[0] * ptv[0];
            #pragma unroll
            for (int w = 1; w < 5; ++w) {
                a0 = fmaf(h0[w], ptv[w], a0);
                a1 = fmaf(h1[w], ptv[w], a1);
                at = fmaf(ht[w], ptv[w], at);
            }
            u0[8] = pk2(a0, pa0[4]);
            u1[8] = pk2(a1, pa1[4]);
            ut[8] = pk2(at, ptv[4]);
        }
        char* yr = (char*)ys + tloc * 656 + 72 * q;  // rows 2q,2q+1: contiguous 72 B
        *(uint2*)(yr +  0) = uint2{u0[0], u0[1]};
        *(uint2*)(yr +  8) = uint2{u0[2], u0[3]};
        *(uint2*)(yr + 16) = uint2{u0[4], u0[5]};
        *(uint2*)(yr + 24) = uint2{u0[6], u0[7]};
        *(uint2*)(yr + 32) = uint2{u0[8], u1[0]};
        *(uint2*)(yr + 40) = uint2{u1[1], u1[2]};
        *(uint2*)(yr + 48) = uint2{u1[3], u1[4]};
        *(uint2*)(yr + 56) = uint2{u1[5], u1[6]};
        *(uint2*)(yr + 64) = uint2{u1[7], u1[8]};
        if (q == 0) {                                // row a=16 at bytes [576,612)
            char* yr16 = (char*)ys + tloc * 656 + 576;
            *(uint2*)(yr16 +  0) = uint2{ut[0], ut[1]};
            *(uint2*)(yr16 +  8) = uint2{ut[2], ut[3]};
            *(uint2*)(yr16 + 16) = uint2{ut[4], ut[5]};
            *(uint2*)(yr16 + 24) = uint2{ut[6], ut[7]};
            *(unsigned*)(yr16 + 32) = ut[8];
        }
    }
    __syncthreads();

    // ---- phase 2: 2 waves = o-halves; y (16x320) @ Wf^T; B-frags global (L2-hot) ----
    {
        f32x4 acc[2];
        #pragma unroll
        for (int cc = 0; cc < 2; ++cc) {
            float bv = bias[(wave * 2 + cc) * 16 + l15];
            acc[cc] = f32x4{bv, bv, bv, bv};
        }
        const char* Ab = (const char*)ys + l15 * 656 + l4 * 16;
        const unsigned short* Bb = Wf + (size_t)l15 * KPAD + l4 * 8;
        #pragma unroll
        for (int kk = 0; kk < 10; ++kk) {
            bf16x8 af = *(const bf16x8*)(Ab + kk * 64);
            #pragma unroll
            for (int cc = 0; cc < 2; ++cc) {
                bf16x8 bfr = *(const bf16x8*)(Bb + (size_t)((wave * 2 + cc) * 16) * KPAD + kk * 32);
                acc[cc] = __builtin_amdgcn_mfma_f32_16x16x32_bf16(af, bfr, acc[cc], 0, 0, 0);
            }
        }
        const int tg = t0 + l4 * 4;                  // row = l4*4 + reg -> t
        #pragma unroll
        for (int cc = 0; cc < 2; ++cc) {
            int o = (wave * 2 + cc) * 16 + l15;
            *(f32x4*)(out + ((size_t)(n * O_DIM + o) * J_DIM + j) * T_DIM + tg) = acc[cc];
        }
    }
}

extern "C" void kernel_launch(void* const* d_in, const int* in_sizes, int n_in,
                              void* d_out, int out_size, void* d_ws, size_t ws_size,
                              hipStream_t stream) {
    const float* x = (const float*)d_in[0];
    const float* W = (const float*)d_in[1];
    const float* b = (const float*)d_in[2];
    float* out = (float*)d_out;
    unsigned short* Wf = (unsigned short*)d_ws;   // 64*328*2 = 41,984 B

    wprep<<<(O_DIM * KPAD + 255) / 256, 256, 0, stream>>>(W, Wf);
    sig_mfma<<<64 * J_DIM * 8, 128, 0, stream>>>(x, Wf, b, out);
}